// Round 6
// baseline (321.141 us; speedup 1.0000x reference)
//
#include <hip/hip_runtime.h>
#include <cstdint>
#include <cstddef>

using bf16x8 = __attribute__((ext_vector_type(8))) short;
using f32x4  = __attribute__((ext_vector_type(4))) float;
using u32x4  = __attribute__((ext_vector_type(4))) unsigned int;

#define DI __device__ __forceinline__

// psum ADC quantization: clip(round_half_even(p/16), -8, 7) * 16   (exact on int psums)
DI float pq16(float ps) {
    float q = rintf(ps * 0.0625f);
    q = fminf(7.f, fmaxf(-8.f, q));
    return q * 16.f;
}

DI float bnv(float x, float g, float b, float m, float v) {
    return (x - m) * (g / sqrtf(v + 1e-5f)) + b;
}

DI unsigned short sgn_bf16(float v) {
    return (v >= 0.f) ? (unsigned short)0x3F80 : (unsigned short)0xBF80;
}

// ---------------- conv0 (full precision) + bn0 + sign -> bf16 NHWC ----------
__global__ __launch_bounds__(256)
void k_conv0(const float* __restrict__ x, const float* __restrict__ w,
             const float* __restrict__ bnp, unsigned short* __restrict__ out) {
    __shared__ float sX[3][3][36];
    const int b = blockIdx.x >> 5, y = blockIdx.x & 31;
    const int tid = threadIdx.x;
    const int o = tid & 127, xc = tid >> 7;

    for (int i = tid; i < 3 * 3 * 36; i += 256) {
        int col = i % 36, rr = (i / 36) % 3, c = i / 108;
        int gy = y + rr - 1, gx = col - 1;
        float v = 0.f;
        if ((unsigned)gy < 32u && (unsigned)gx < 32u)
            v = x[((b * 3 + c) * 32 + gy) * 32 + gx];
        sX[c][rr][col] = v;
    }
    float wr[27];
    const float* wp = w + o * 27;
    #pragma unroll
    for (int t = 0; t < 27; ++t) wr[t] = wp[t];
    __syncthreads();

    const float bg = bnp[o], bb = bnp[128 + o], bm = bnp[256 + o], bv = bnp[384 + o];
    unsigned short* op = out + ((size_t)(b * 32 + y) * 32) * 128 + o;

    #pragma unroll
    for (int q = 0; q < 4; ++q) {
        float acc0 = 0.f, acc1 = 0.f, acc2 = 0.f, acc3 = 0.f;
        const int X0 = xc * 16 + q * 4;
        #pragma unroll
        for (int c = 0; c < 3; ++c)
            #pragma unroll
            for (int ky = 0; ky < 3; ++ky) {
                float xv0 = sX[c][ky][X0 + 0], xv1 = sX[c][ky][X0 + 1];
                float xv2 = sX[c][ky][X0 + 2], xv3 = sX[c][ky][X0 + 3];
                float xv4 = sX[c][ky][X0 + 4], xv5 = sX[c][ky][X0 + 5];
                float w0 = wr[c * 9 + ky * 3 + 0];
                float w1 = wr[c * 9 + ky * 3 + 1];
                float w2 = wr[c * 9 + ky * 3 + 2];
                acc0 += xv0 * w0 + xv1 * w1 + xv2 * w2;
                acc1 += xv1 * w0 + xv2 * w1 + xv3 * w2;
                acc2 += xv2 * w0 + xv3 * w1 + xv4 * w2;
                acc3 += xv3 * w0 + xv4 * w1 + xv5 * w2;
            }
        op[(size_t)(X0 + 0) * 128] = sgn_bf16(bnv(acc0, bg, bb, bm, bv));
        op[(size_t)(X0 + 1) * 128] = sgn_bf16(bnv(acc1, bg, bb, bm, bv));
        op[(size_t)(X0 + 2) * 128] = sgn_bf16(bnv(acc2, bg, bb, bm, bv));
        op[(size_t)(X0 + 3) * 128] = sgn_bf16(bnv(acc3, bg, bb, bm, bv));
    }
}

// ---------------- weight sign-pack: wpk[g][o][tap(10)][c(16)] bf16 ----------
__global__ __launch_bounds__(256)
void k_pack_w(const float* __restrict__ w, unsigned short* __restrict__ wpk,
              int Cin, int O, int G) {
    int idx = blockIdx.x * 256 + threadIdx.x;
    int total = G * O * 160;
    if (idx >= total) return;
    int c = idx & 15;
    int tap = (idx >> 4) % 10;
    int rest = idx / 160;
    int o = rest % O, g = rest / O;
    unsigned short v = 0;
    int cg = g * 14 + c;
    if (tap < 9 && c < 14 && cg < Cin)
        v = sgn_bf16(w[((size_t)o * Cin + cg) * 9 + tap]);
    wpk[idx] = v;
}

// ---------------- MFMA crossbar psum conv ------------------------------------
// POOLMODE: 0 = bn+sign -> NHWC; 1 = pool+bn+sign -> NHWC (RW==16);
//           2 = pool+bn+sign -> packed a5p (RW==8); 3 = atomicAdd f32 -> P (K-split);
//           4 = pool+bn+sign -> NHWC (RW==8, cross-lane pool)
template <int H, int W, int Cin, int O, int RH, int RW, int POOLMODE>
__global__ __launch_bounds__(256)
void k_conv_mfma(const unsigned int* __restrict__ act,
                 const unsigned short* __restrict__ wpk,
                 const float* __restrict__ bnp,
                 unsigned short* __restrict__ outa,
                 unsigned short* __restrict__ a5p,
                 float* __restrict__ Pacc,
                 int gsz, int Gtot) {
    constexpr int SH = RH + 2, SW = RW + 2;
    constexpr int MS = RH * RW / 16;
    constexpr int NREGX = W / RW;
    constexpr int NTILES = (H / RH) * (W / RW);
    static_assert(POOLMODE != 1 || RW == 16, "pool mode 1 needs RW=16");
    static_assert((POOLMODE != 2 && POOLMODE != 4) || (RW == 8 && MS == 4), "modes 2/4 need 8x8");

    __shared__ __align__(16) unsigned int sA[SH * SW * 12];  // 48B per pixel slot

    const int tid  = threadIdx.x;
    const int bx   = (int)blockIdx.x;
    const int tile = bx % NTILES, chunk = bx / NTILES;
    const int regY = tile / NREGX, regX = tile % NREGX;
    const int o0   = blockIdx.y * 64;
    const int b    = blockIdx.z;
    const int g0   = chunk * gsz;
    const int gend = min(g0 + gsz, Gtot);

    const int lane = tid & 63, wv = tid >> 6;
    const int n  = lane & 15;
    const int kb = lane >> 4;
    const int hb = kb >> 1, ch = kb & 1;

    int baseA[MS];
    #pragma unroll
    for (int ms = 0; ms < MS; ++ms) {
        int p = ms * 16 + n;
        int y = p / RW, x = p % RW;
        baseA[ms] = (y * SW + x) * 48 + ch * 16;
    }

    float tot[MS][4];
    #pragma unroll
    for (int ms = 0; ms < MS; ++ms) {
        tot[ms][0] = 0.f; tot[ms][1] = 0.f; tot[ms][2] = 0.f; tot[ms][3] = 0.f;
    }

    const unsigned short* wrow = wpk + ((size_t)o0 + wv * 16 + n) * 160 + ch * 8;

    #pragma unroll 1
    for (int g = g0; g < gend; ++g) {
        const int rem_dw = (Cin - g * 14) >> 1;
        for (int i = tid; i < SH * SW * 8; i += 256) {
            int cp = i & 7, slot = i >> 3;
            int yy = slot / SW, xx = slot - yy * SW;
            int gy = regY * RH + yy - 1, gx = regX * RW + xx - 1;
            unsigned int v = 0;
            if (cp < 7 && cp < rem_dw &&
                (unsigned)gy < (unsigned)H && (unsigned)gx < (unsigned)W)
                v = act[(((size_t)b * H + gy) * W + gx) * (Cin / 2) + g * 7 + cp];
            sA[slot * 12 + cp] = v;
        }
        const unsigned short* wg = wrow + (size_t)g * O * 160;
        bf16x8 bq[5];
        #pragma unroll
        for (int s = 0; s < 5; ++s) {
            int tap = 2 * s + hb;
            bq[s] = *(const bf16x8*)(wg + tap * 16);
        }
        __syncthreads();

        const char* sAc = (const char*)sA;
        #pragma unroll
        for (int ms = 0; ms < MS; ++ms) {
            f32x4 acc = {0.f, 0.f, 0.f, 0.f};
            #pragma unroll
            for (int s = 0; s < 5; ++s) {
                const int t0 = 2 * s, t1 = 2 * s + 1;
                const int off0 = ((t0 / 3) * SW + (t0 % 3)) * 48;
                const int off1 = (t1 >= 9) ? 0 : ((t1 / 3) * SW + (t1 % 3)) * 48;
                int off = hb ? off1 : off0;
                bf16x8 af = *(const bf16x8*)(sAc + baseA[ms] + off);
                acc = __builtin_amdgcn_mfma_f32_16x16x32_bf16(af, bq[s], acc, 0, 0, 0);
            }
            tot[ms][0] += pq16(acc[0]);
            tot[ms][1] += pq16(acc[1]);
            tot[ms][2] += pq16(acc[2]);
            tot[ms][3] += pq16(acc[3]);
        }
        __syncthreads();
    }

    const int oc = o0 + wv * 16 + n;

    if constexpr (POOLMODE == 3) {
        #pragma unroll
        for (int ms = 0; ms < MS; ++ms)
            #pragma unroll
            for (int r = 0; r < 4; ++r) {
                int p = ms * 16 + 4 * kb + r;
                int y = regY * RH + p / RW, x = regX * RW + p % RW;
                atomicAdd(&Pacc[(((size_t)b * H + y) * W + x) * O + oc], tot[ms][r]);
            }
        return;
    }

    const float bg = bnp[oc], bb = bnp[O + oc], bm = bnp[2 * O + oc], bvr = bnp[3 * O + oc];

    if constexpr (POOLMODE == 0) {
        #pragma unroll
        for (int ms = 0; ms < MS; ++ms)
            #pragma unroll
            for (int r = 0; r < 4; ++r) {
                int p = ms * 16 + 4 * kb + r;
                int y = regY * RH + p / RW, x = regX * RW + p % RW;
                float val = bnv(tot[ms][r], bg, bb, bm, bvr);
                outa[(((size_t)b * H + y) * W + x) * O + oc] = sgn_bf16(val);
            }
    } else if constexpr (POOLMODE == 1) {
        #pragma unroll
        for (int j = 0; j < MS / 2; ++j)
            #pragma unroll
            for (int q = 0; q < 2; ++q) {
                float v = fmaxf(fmaxf(tot[2 * j][2 * q], tot[2 * j][2 * q + 1]),
                                fmaxf(tot[2 * j + 1][2 * q], tot[2 * j + 1][2 * q + 1]));
                float val = bnv(v, bg, bb, bm, bvr);
                int py = regY * (RH / 2) + j, px = regX * (RW / 2) + 2 * kb + q;
                outa[(((size_t)b * (H / 2) + py) * (W / 2) + px) * O + oc] = sgn_bf16(val);
            }
    } else {
        // modes 2/4: RW==8 pooling; y=2*ms+hb, x=4*ch+r; vertical partner lane^32
        #pragma unroll
        for (int ms = 0; ms < MS; ++ms)
            #pragma unroll
            for (int q = 0; q < 2; ++q) {
                float h = fmaxf(tot[ms][2 * q], tot[ms][2 * q + 1]);
                float o2 = __shfl_xor(h, 32);
                float v = fmaxf(h, o2);
                if (hb == 0) {
                    float val = bnv(v, bg, bb, bm, bvr);
                    int py = ms, px = 2 * ch + q;
                    if constexpr (POOLMODE == 2) {
                        int d = oc * 16 + py * 4 + px;   // NCHW flatten order
                        a5p[((size_t)(d >> 3) * 64 + b) * 8 + (d & 7)] = sgn_bf16(val);
                    } else {
                        int gpy = regY * (RH / 2) + py, gpx = regX * (RW / 2) + px;
                        outa[(((size_t)b * (H / 2) + gpy) * (W / 2) + gpx) * O + oc] = sgn_bf16(val);
                    }
                }
            }
    }
}

// ---------------- L4 epilogue: bn+sign on f32 psum -> NHWC bf16 --------------
template <int O>
__global__ __launch_bounds__(256)
void k_ep_bnsign(const float* __restrict__ P, const float* __restrict__ bnp,
                 unsigned short* __restrict__ outa) {
    int idx = blockIdx.x * 256 + threadIdx.x;
    int o = idx & (O - 1);
    float val = bnv(P[idx], bnp[o], bnp[O + o], bnp[2 * O + o], bnp[3 * O + o]);
    outa[idx] = sgn_bf16(val);
}

// ---------------- L5 epilogue: pool+bn+sign on f32 psum -> packed a5p --------
__global__ __launch_bounds__(256)
void k_ep_pool_pack(const float* __restrict__ P, const float* __restrict__ bnp,
                    unsigned short* __restrict__ a5p) {
    int idx = blockIdx.x * 256 + threadIdx.x;   // 64*4*4*512, o innermost
    int o = idx & 511;
    int px = (idx >> 9) & 3, py = (idx >> 11) & 3, b = idx >> 13;
    const float* base = P + (((size_t)b * 8 + 2 * py) * 8 + 2 * px) * 512 + o;
    float v = fmaxf(fmaxf(base[0], base[512]), fmaxf(base[8 * 512], base[8 * 512 + 512]));
    float val = bnv(v, bnp[o], bnp[512 + o], bnp[1024 + o], bnp[1536 + o]);
    int d = o * 16 + py * 4 + px;   // NCHW flatten order
    a5p[((size_t)(d >> 3) * 64 + b) * 8 + (d & 7)] = sgn_bf16(val);
}

// ---------------- MFMA psum fc ----------------------------------------------
template <int D, int GPB>
__global__ __launch_bounds__(256)
void k_fc_mfma(const unsigned short* __restrict__ bpk, const float* __restrict__ w,
               float* __restrict__ accg) {
    const int lane = threadIdx.x & 63, wv = threadIdx.x >> 6;
    const int n = lane & 15, kb = lane >> 4;
    const int orow = blockIdx.x * 64 + wv * 16 + n;
    const int g0 = blockIdx.y * GPB;

    float tot[4][4];
    #pragma unroll
    for (int s = 0; s < 4; ++s)
        #pragma unroll
        for (int r = 0; r < 4; ++r) tot[s][r] = 0.f;

    #pragma unroll 1
    for (int g = 0; g < GPB; ++g) {
        const int kbase = (g0 + g) * 128;
        f32x4 a0 = {0,0,0,0}, a1 = {0,0,0,0}, a2 = {0,0,0,0}, a3 = {0,0,0,0};
        #pragma unroll
        for (int s = 0; s < 4; ++s) {
            const int k0 = kbase + s * 32 + kb * 8;
            const float* wp = w + (size_t)orow * D + k0;
            float4 wlo = *(const float4*)wp;
            float4 whi = *(const float4*)(wp + 4);
            bf16x8 af;
            af[0] = (short)sgn_bf16(wlo.x); af[1] = (short)sgn_bf16(wlo.y);
            af[2] = (short)sgn_bf16(wlo.z); af[3] = (short)sgn_bf16(wlo.w);
            af[4] = (short)sgn_bf16(whi.x); af[5] = (short)sgn_bf16(whi.y);
            af[6] = (short)sgn_bf16(whi.z); af[7] = (short)sgn_bf16(whi.w);
            const unsigned short* bp = bpk + (size_t)(k0 >> 3) * 512;
            bf16x8 b0 = *(const bf16x8*)(bp + (n +  0) * 8);
            bf16x8 b1 = *(const bf16x8*)(bp + (n + 16) * 8);
            bf16x8 b2 = *(const bf16x8*)(bp + (n + 32) * 8);
            bf16x8 b3 = *(const bf16x8*)(bp + (n + 48) * 8);
            a0 = __builtin_amdgcn_mfma_f32_16x16x32_bf16(af, b0, a0, 0, 0, 0);
            a1 = __builtin_amdgcn_mfma_f32_16x16x32_bf16(af, b1, a1, 0, 0, 0);
            a2 = __builtin_amdgcn_mfma_f32_16x16x32_bf16(af, b2, a2, 0, 0, 0);
            a3 = __builtin_amdgcn_mfma_f32_16x16x32_bf16(af, b3, a3, 0, 0, 0);
        }
        #pragma unroll
        for (int r = 0; r < 4; ++r) {
            tot[0][r] += pq16(a0[r]); tot[1][r] += pq16(a1[r]);
            tot[2][r] += pq16(a2[r]); tot[3][r] += pq16(a3[r]);
        }
    }
    const int od = blockIdx.x * 64 + wv * 16 + kb * 4;
    #pragma unroll
    for (int s = 0; s < 4; ++s)
        #pragma unroll
        for (int r = 0; r < 4; ++r)
            atomicAdd(&accg[(size_t)(od + r) * 64 + s * 16 + n], tot[s][r]);
}

// ---------------- fc epilogue: bn (+sign+pack) ------------------------------
template <bool SIGN>
__global__ __launch_bounds__(256)
void k_fc_ep(const float* __restrict__ accg, const float* __restrict__ bnp,
             unsigned short* __restrict__ packed, float* __restrict__ h2, int O) {
    int idx = blockIdx.x * 256 + threadIdx.x;   // O*64
    int b = idx & 63, o = idx >> 6;
    float val = bnv(accg[idx], bnp[o], bnp[O + o], bnp[2 * O + o], bnp[3 * O + o]);
    if (SIGN) packed[((size_t)(o >> 3) * 64 + b) * 8 + (o & 7)] = sgn_bf16(val);
    else      h2[(size_t)b * 1024 + o] = val;
}

// ---------------- final dense + bias + bn: one wave per (b,o) ---------------
__global__ __launch_bounds__(64)
void k_out(const float* __restrict__ h2, const float* __restrict__ ow,
           const float* __restrict__ ob, const float* __restrict__ bnp,
           float* __restrict__ out) {
    int b = blockIdx.x / 10, o = blockIdx.x % 10;
    int lane = threadIdx.x;
    float acc = 0.f;
    #pragma unroll
    for (int i = 0; i < 16; ++i) {
        int k = i * 64 + lane;
        acc += h2[b * 1024 + k] * ow[o * 1024 + k];
    }
    #pragma unroll
    for (int off = 32; off; off >>= 1) acc += __shfl_xor(acc, off);
    if (lane == 0)
        out[b * 10 + o] = bnv(acc + ob[o], bnp[o], bnp[10 + o], bnp[20 + o], bnp[30 + o]);
}

extern "C" void kernel_launch(void* const* d_in, const int* in_sizes, int n_in,
                              void* d_out, int out_size, void* d_ws, size_t ws_size,
                              hipStream_t stream) {
    const float* x     = (const float*)d_in[0];
    const float* w0    = (const float*)d_in[1];
    const float* bn0   = (const float*)d_in[2];
    const float* w1    = (const float*)d_in[3];
    const float* bn1   = (const float*)d_in[4];
    const float* w2    = (const float*)d_in[5];
    const float* bn2   = (const float*)d_in[6];
    const float* w3    = (const float*)d_in[7];
    const float* bn3   = (const float*)d_in[8];
    const float* w4    = (const float*)d_in[9];
    const float* bn4   = (const float*)d_in[10];
    const float* w5    = (const float*)d_in[11];
    const float* bn5   = (const float*)d_in[12];
    const float* fc1w  = (const float*)d_in[13];
    const float* bnf1  = (const float*)d_in[14];
    const float* fc2w  = (const float*)d_in[15];
    const float* bnf2  = (const float*)d_in[16];
    const float* outw  = (const float*)d_in[17];
    const float* outb  = (const float*)d_in[18];
    const float* bnout = (const float*)d_in[19];

    char* ws = (char*)d_ws;
    unsigned short* actA  = (unsigned short*)(ws);              // 16,777,216 B
    unsigned short* actB  = (unsigned short*)(ws + 16777216);   //  4,194,304 B
    unsigned short* wpk   = (unsigned short*)(ws + 20971520);   //  6,291,456 B
    float*          P     = (float*)(ws + 27262976);            //  8,388,608 B [64,8,8,512] f32
    unsigned short* a5p   = (unsigned short*)(ws + 35651584);   //  1,048,576 B
    unsigned short* a6p   = (unsigned short*)(ws + 36700160);   //    131,072 B
    float*          h1acc = (float*)(ws + 36831232);            //    262,144 B
    float*          h2acc = (float*)(ws + 37093376);            //    262,144 B
    float*          h2    = (float*)(ws + 37355520);            //    262,144 B

    const unsigned int* actA32 = (const unsigned int*)actA;
    const unsigned int* actB32 = (const unsigned int*)actB;

    hipMemsetAsync(h1acc, 0, 262144, stream);
    hipMemsetAsync(h2acc, 0, 262144, stream);

    // conv0 + bn0 + sign -> actA NHWC bf16 [64,32,32,128]
    k_conv0<<<dim3(2048), dim3(256), 0, stream>>>(x, w0, bn0, actA);

    // L1: 128->128 @32, pool fused -> actB [64,16,16,128]
    k_pack_w<<<dim3(800), dim3(256), 0, stream>>>(w1, wpk, 128, 128, 10);
    k_conv_mfma<32, 32, 128, 128, 8, 16, 1>
        <<<dim3(8, 2, 64), dim3(256), 0, stream>>>(actA32, wpk, bn1, actB, nullptr, nullptr, 10, 10);

    // L2: 128->256 @16 fused (8x8 tiles) -> actA [64,16,16,256]
    k_pack_w<<<dim3(1600), dim3(256), 0, stream>>>(w2, wpk, 128, 256, 10);
    k_conv_mfma<16, 16, 128, 256, 8, 8, 0>
        <<<dim3(4, 4, 64), dim3(256), 0, stream>>>(actB32, wpk, bn2, actA, nullptr, nullptr, 10, 10);

    // L3: 256->256 @16, pool fused (8x8 tiles) -> actB [64,8,8,256]
    k_pack_w<<<dim3(3040), dim3(256), 0, stream>>>(w3, wpk, 256, 256, 19);
    k_conv_mfma<16, 16, 256, 256, 8, 8, 4>
        <<<dim3(4, 4, 64), dim3(256), 0, stream>>>(actA32, wpk, bn3, actB, nullptr, nullptr, 19, 19);

    // L4: 256->512 @8, K-split x4 -> P, then bn+sign -> actA [64,8,8,512]
    k_pack_w<<<dim3(6080), dim3(256), 0, stream>>>(w4, wpk, 256, 512, 19);
    hipMemsetAsync(P, 0, 8388608, stream);
    k_conv_mfma<8, 8, 256, 512, 8, 8, 3>
        <<<dim3(4, 8, 64), dim3(256), 0, stream>>>(actB32, wpk, nullptr, nullptr, nullptr, P, 5, 19);
    k_ep_bnsign<512><<<dim3(8192), dim3(256), 0, stream>>>(P, bn4, actA);

    // L5: 512->512 @8, K-split x4 -> P, then pool+bn+sign -> a5p packed
    k_pack_w<<<dim3(11840), dim3(256), 0, stream>>>(w5, wpk, 512, 512, 37);
    hipMemsetAsync(P, 0, 8388608, stream);
    k_conv_mfma<8, 8, 512, 512, 8, 8, 3>
        <<<dim3(4, 8, 64), dim3(256), 0, stream>>>(actA32, wpk, nullptr, nullptr, nullptr, P, 10, 37);
    k_ep_pool_pack<<<dim3(2048), dim3(256), 0, stream>>>(P, bn5, a5p);

    // fc1: D=8192, 16 o-tiles x 64 k-chunks (1 group each)
    k_fc_mfma<8192, 1><<<dim3(16, 64), dim3(256), 0, stream>>>(a5p, fc1w, h1acc);
    k_fc_ep<true><<<dim3(256), dim3(256), 0, stream>>>(h1acc, bnf1, a6p, nullptr, 1024);

    // fc2: D=1024, 16 o-tiles x 8 k-chunks
    k_fc_mfma<1024, 1><<<dim3(16, 8), dim3(256), 0, stream>>>(a6p, fc2w, h2acc);
    k_fc_ep<false><<<dim3(256), dim3(256), 0, stream>>>(h2acc, bnf2, nullptr, h2, 1024);

    // out
    k_out<<<dim3(640), dim3(64), 0, stream>>>(h2, outw, outb, bnout, (float*)d_out);
}